// Round 1
// baseline (477.653 us; speedup 1.0000x reference)
//
#include <hip/hip_runtime.h>

#define TSTEPS 2048
#define BCOLS  8192
#define TBSZ   (TSTEPS * BCOLS)

__global__ __launch_bounds__(64)
void seir_kernel(const float* __restrict__ X,
                 const float* __restrict__ w_beta,
                 const float* __restrict__ w_gamma,
                 const float* __restrict__ w_sigma,
                 const float* __restrict__ S0,
                 const float* __restrict__ I0,
                 const float* __restrict__ R0,
                 const float* __restrict__ Nv,
                 float* __restrict__ out)
{
    const int b = blockIdx.x * 64 + threadIdx.x;

    const float wb = w_beta[b];
    const float wg = w_gamma[b];
    const float ws = w_sigma[b];
    float S = S0[b];
    float E = 0.0f;
    float I = I0[b];
    float R = R0[b];
    const float invN = 1.0f / Nv[b];

    float* oS = out + b;
    float* oE = out + (size_t)TBSZ + b;
    float* oI = out + (size_t)2 * TBSZ + b;
    float* oR = out + (size_t)3 * TBSZ + b;

    // t = 0 row: initial state (E0 = 0 exactly)
    __builtin_nontemporal_store(S, oS);
    __builtin_nontemporal_store(0.0f, oE);
    __builtin_nontemporal_store(I, oI);
    __builtin_nontemporal_store(R, oR);

    const float* xp = X + b;
    float xc[8];
#pragma unroll
    for (int k = 0; k < 8; ++k)
        xc[k] = __builtin_nontemporal_load(xp + (size_t)k * BCOLS);
    xp += (size_t)8 * BCOLS;

    // chunk i covers steps t = 8i+1 .. 8i+8 (consuming X rows 8i .. 8i+7)
    for (int i = 0; i < 255; ++i) {
        float xn[8];
#pragma unroll
        for (int k = 0; k < 8; ++k)
            xn[k] = __builtin_nontemporal_load(xp + (size_t)k * BCOLS);
        xp += (size_t)8 * BCOLS;

        float* pS = oS + (size_t)(8 * i + 1) * BCOLS;
        float* pE = oE + (size_t)(8 * i + 1) * BCOLS;
        float* pI = oI + (size_t)(8 * i + 1) * BCOLS;
        float* pR = oR + (size_t)(8 * i + 1) * BCOLS;

#pragma unroll
        for (int k = 0; k < 8; ++k) {
            const float x   = xc[k];
            const float s2e = x * wb * I * S * invN;
            const float e2i = x * ws * E;
            const float i2r = x * wg * I;
            S = S - s2e;
            E = E + s2e - e2i;
            I = I + e2i - i2r;
            R = R + i2r;
            __builtin_nontemporal_store(S, pS + (size_t)k * BCOLS);
            __builtin_nontemporal_store(E, pE + (size_t)k * BCOLS);
            __builtin_nontemporal_store(I, pI + (size_t)k * BCOLS);
            __builtin_nontemporal_store(R, pR + (size_t)k * BCOLS);
        }
#pragma unroll
        for (int k = 0; k < 8; ++k) xc[k] = xn[k];
    }

    // tail: steps t = 2041 .. 2047 (X rows 2040 .. 2046 → xc[0..6])
    {
        float* pS = oS + (size_t)2041 * BCOLS;
        float* pE = oE + (size_t)2041 * BCOLS;
        float* pI = oI + (size_t)2041 * BCOLS;
        float* pR = oR + (size_t)2041 * BCOLS;
#pragma unroll
        for (int k = 0; k < 7; ++k) {
            const float x   = xc[k];
            const float s2e = x * wb * I * S * invN;
            const float e2i = x * ws * E;
            const float i2r = x * wg * I;
            S = S - s2e;
            E = E + s2e - e2i;
            I = I + e2i - i2r;
            R = R + i2r;
            __builtin_nontemporal_store(S, pS + (size_t)k * BCOLS);
            __builtin_nontemporal_store(E, pE + (size_t)k * BCOLS);
            __builtin_nontemporal_store(I, pI + (size_t)k * BCOLS);
            __builtin_nontemporal_store(R, pR + (size_t)k * BCOLS);
        }
    }
}

extern "C" void kernel_launch(void* const* d_in, const int* in_sizes, int n_in,
                              void* d_out, int out_size, void* d_ws, size_t ws_size,
                              hipStream_t stream)
{
    const float* X      = (const float*)d_in[0];
    const float* w_beta = (const float*)d_in[1];
    const float* w_gamma= (const float*)d_in[2];
    const float* w_sigma= (const float*)d_in[3];
    const float* S0     = (const float*)d_in[4];
    const float* I0     = (const float*)d_in[5];
    const float* R0     = (const float*)d_in[6];
    const float* Nv     = (const float*)d_in[7];
    float* out          = (float*)d_out;

    seir_kernel<<<dim3(BCOLS / 64), dim3(64), 0, stream>>>(
        X, w_beta, w_gamma, w_sigma, S0, I0, R0, Nv, out);
}

// Round 2
// 381.005 us; speedup vs baseline: 1.2537x; 1.2537x over previous
//
#include <hip/hip_runtime.h>

#define TSTEPS 2048
#define BCOLS  8192
#define TBSZ   (TSTEPS * BCOLS)
#define CHUNKS 32
#define CLEN   64          // TSTEPS / CHUNKS

// One SEIR step. Shared by all kernels so rounding is identical everywhere.
__device__ __forceinline__ void seir_step(float x, float wb, float wg, float wsg,
                                          float invN,
                                          float& S, float& E, float& I, float& R)
{
    const float s2e = x * wb * I * S * invN;
    const float e2i = x * wsg * E;
    const float i2r = x * wg * I;
    S = S - s2e;
    E = E + s2e - e2i;
    I = I + e2i - i2r;
    R = R + i2r;
}

// ---------------------------------------------------------------------------
// Pass 1: sequential recurrence, compute-only, save states at chunk boundaries.
// Saves state AFTER consuming X row t for t = 62, 126, ..., 1982 (t ≡ 62 mod 64)
// → that is output row t+1 = 64c-1, the start state for chunk c = idx+1.
// ---------------------------------------------------------------------------
__global__ __launch_bounds__(64)
void seir_pass1(const float* __restrict__ X,
                const float* __restrict__ w_beta,
                const float* __restrict__ w_gamma,
                const float* __restrict__ w_sigma,
                const float* __restrict__ S0,
                const float* __restrict__ I0,
                const float* __restrict__ R0,
                const float* __restrict__ Nv,
                float* __restrict__ wsp)
{
    const int b = blockIdx.x * 64 + threadIdx.x;

    const float wb  = w_beta[b];
    const float wg  = w_gamma[b];
    const float wsg = w_sigma[b];
    float S = S0[b];
    float E = 0.0f;
    float I = I0[b];
    float R = R0[b];
    const float invN = 1.0f / Nv[b];

    const float* xp = X + b;
    float xbuf[48];                       // 48-deep prefetch ring
#pragma unroll
    for (int k = 0; k < 48; ++k)
        xbuf[k] = xp[(size_t)k * BCOLS];
    xp += (size_t)48 * BCOLS;

    // 41 blocks of 48 steps (t = 0..1967), then 15 drain steps (t = 1968..1982)
    for (int j = 0; j < 41; ++j) {
        const int tbase = j * 48;
#pragma unroll
        for (int k = 0; k < 48; ++k) {
            const float x = xbuf[k];
            xbuf[k] = xp[(size_t)k * BCOLS];   // prefetch row tbase+48+k (max 2015)
            seir_step(x, wb, wg, wsg, invN, S, E, I, R);
            const int t = tbase + k;
            if (((t - 62) & 63) == 0) {        // t ≡ 62 (mod 64)
                const int idx = (t - 62) >> 6; // 0..30
                float* wp = wsp + (size_t)idx * 4 * BCOLS + b;
                wp[0]                  = S;
                wp[(size_t)BCOLS]      = E;
                wp[(size_t)2 * BCOLS]  = I;
                wp[(size_t)3 * BCOLS]  = R;
            }
        }
        xp += (size_t)48 * BCOLS;
    }
#pragma unroll
    for (int k = 0; k < 15; ++k) {             // t = 1968 + k
        const float x = xbuf[k];
        seir_step(x, wb, wg, wsg, invN, S, E, I, R);
        if (((1968 + k - 62) & 63) == 0) {     // k == 14 → t = 1982, idx 30
            const int idx = (1968 + k - 62) >> 6;
            float* wp = wsp + (size_t)idx * 4 * BCOLS + b;
            wp[0]                  = S;
            wp[(size_t)BCOLS]      = E;
            wp[(size_t)2 * BCOLS]  = I;
            wp[(size_t)3 * BCOLS]  = R;
        }
    }
}

// ---------------------------------------------------------------------------
// Pass 2: each block replays one 64-step chunk from its saved state and
// streams all outputs. NS steps, fully unrolled with an 8-deep prefetch ring.
// ---------------------------------------------------------------------------
template <int NS>
__device__ __forceinline__ void run_chunk(const float* __restrict__ xp,
                                          float* __restrict__ pS,
                                          float* __restrict__ pE,
                                          float* __restrict__ pI,
                                          float* __restrict__ pR,
                                          float wb, float wg, float wsg, float invN,
                                          float S, float E, float I, float R)
{
    float xbuf[8];
#pragma unroll
    for (int k = 0; k < 8; ++k)
        xbuf[k] = xp[(size_t)k * BCOLS];
#pragma unroll
    for (int t = 0; t < NS; ++t) {
        const float x = xbuf[t & 7];
        if (t + 8 < NS)
            xbuf[t & 7] = xp[(size_t)(t + 8) * BCOLS];
        seir_step(x, wb, wg, wsg, invN, S, E, I, R);
        __builtin_nontemporal_store(S, pS + (size_t)t * BCOLS);
        __builtin_nontemporal_store(E, pE + (size_t)t * BCOLS);
        __builtin_nontemporal_store(I, pI + (size_t)t * BCOLS);
        __builtin_nontemporal_store(R, pR + (size_t)t * BCOLS);
    }
}

__global__ __launch_bounds__(64)
void seir_pass2(const float* __restrict__ X,
                const float* __restrict__ w_beta,
                const float* __restrict__ w_gamma,
                const float* __restrict__ w_sigma,
                const float* __restrict__ S0,
                const float* __restrict__ I0,
                const float* __restrict__ R0,
                const float* __restrict__ Nv,
                const float* __restrict__ wsp,
                float* __restrict__ out)
{
    const int b = blockIdx.x * 64 + threadIdx.x;
    const int c = blockIdx.y;

    const float wb  = w_beta[b];
    const float wg  = w_gamma[b];
    const float wsg = w_sigma[b];
    const float invN = 1.0f / Nv[b];

    float* oS = out + b;
    float* oE = out + (size_t)TBSZ + b;
    float* oI = out + (size_t)2 * TBSZ + b;
    float* oR = out + (size_t)3 * TBSZ + b;

    if (c == 0) {
        float S = S0[b];
        float E = 0.0f;
        float I = I0[b];
        float R = R0[b];
        __builtin_nontemporal_store(S, oS);
        __builtin_nontemporal_store(0.0f, oE);
        __builtin_nontemporal_store(I, oI);
        __builtin_nontemporal_store(R, oR);
        run_chunk<63>(X + b,
                      oS + BCOLS, oE + BCOLS, oI + BCOLS, oR + BCOLS,
                      wb, wg, wsg, invN, S, E, I, R);
    } else {
        const float* wp = wsp + (size_t)(c - 1) * 4 * BCOLS + b;
        const float S = wp[0];
        const float E = wp[(size_t)BCOLS];
        const float I = wp[(size_t)2 * BCOLS];
        const float R = wp[(size_t)3 * BCOLS];
        const size_t t0 = (size_t)c * CLEN - 1;       // first X row consumed
        const size_t r0 = (size_t)c * CLEN;           // first output row written
        run_chunk<64>(X + t0 * BCOLS + b,
                      oS + r0 * BCOLS, oE + r0 * BCOLS,
                      oI + r0 * BCOLS, oR + r0 * BCOLS,
                      wb, wg, wsg, invN, S, E, I, R);
    }
}

// ---------------------------------------------------------------------------
// Fallback: R1 single-kernel version (used only if ws_size is too small).
// ---------------------------------------------------------------------------
__global__ __launch_bounds__(64)
void seir_mono(const float* __restrict__ X,
               const float* __restrict__ w_beta,
               const float* __restrict__ w_gamma,
               const float* __restrict__ w_sigma,
               const float* __restrict__ S0,
               const float* __restrict__ I0,
               const float* __restrict__ R0,
               const float* __restrict__ Nv,
               float* __restrict__ out)
{
    const int b = blockIdx.x * 64 + threadIdx.x;
    const float wb  = w_beta[b];
    const float wg  = w_gamma[b];
    const float wsg = w_sigma[b];
    float S = S0[b];
    float E = 0.0f;
    float I = I0[b];
    float R = R0[b];
    const float invN = 1.0f / Nv[b];

    float* oS = out + b;
    float* oE = out + (size_t)TBSZ + b;
    float* oI = out + (size_t)2 * TBSZ + b;
    float* oR = out + (size_t)3 * TBSZ + b;

    __builtin_nontemporal_store(S, oS);
    __builtin_nontemporal_store(0.0f, oE);
    __builtin_nontemporal_store(I, oI);
    __builtin_nontemporal_store(R, oR);

    const float* xp = X + b;
    float xc[8];
#pragma unroll
    for (int k = 0; k < 8; ++k)
        xc[k] = __builtin_nontemporal_load(xp + (size_t)k * BCOLS);
    xp += (size_t)8 * BCOLS;

    for (int i = 0; i < 255; ++i) {
        float xn[8];
#pragma unroll
        for (int k = 0; k < 8; ++k)
            xn[k] = __builtin_nontemporal_load(xp + (size_t)k * BCOLS);
        xp += (size_t)8 * BCOLS;

        float* pS = oS + (size_t)(8 * i + 1) * BCOLS;
        float* pE = oE + (size_t)(8 * i + 1) * BCOLS;
        float* pI = oI + (size_t)(8 * i + 1) * BCOLS;
        float* pR = oR + (size_t)(8 * i + 1) * BCOLS;

#pragma unroll
        for (int k = 0; k < 8; ++k) {
            seir_step(xc[k], wb, wg, wsg, invN, S, E, I, R);
            __builtin_nontemporal_store(S, pS + (size_t)k * BCOLS);
            __builtin_nontemporal_store(E, pE + (size_t)k * BCOLS);
            __builtin_nontemporal_store(I, pI + (size_t)k * BCOLS);
            __builtin_nontemporal_store(R, pR + (size_t)k * BCOLS);
        }
#pragma unroll
        for (int k = 0; k < 8; ++k) xc[k] = xn[k];
    }
    {
        float* pS = oS + (size_t)2041 * BCOLS;
        float* pE = oE + (size_t)2041 * BCOLS;
        float* pI = oI + (size_t)2041 * BCOLS;
        float* pR = oR + (size_t)2041 * BCOLS;
#pragma unroll
        for (int k = 0; k < 7; ++k) {
            seir_step(xc[k], wb, wg, wsg, invN, S, E, I, R);
            __builtin_nontemporal_store(S, pS + (size_t)k * BCOLS);
            __builtin_nontemporal_store(E, pE + (size_t)k * BCOLS);
            __builtin_nontemporal_store(I, pI + (size_t)k * BCOLS);
            __builtin_nontemporal_store(R, pR + (size_t)k * BCOLS);
        }
    }
}

extern "C" void kernel_launch(void* const* d_in, const int* in_sizes, int n_in,
                              void* d_out, int out_size, void* d_ws, size_t ws_size,
                              hipStream_t stream)
{
    const float* X      = (const float*)d_in[0];
    const float* w_beta = (const float*)d_in[1];
    const float* w_gamma= (const float*)d_in[2];
    const float* w_sigma= (const float*)d_in[3];
    const float* S0     = (const float*)d_in[4];
    const float* I0     = (const float*)d_in[5];
    const float* R0     = (const float*)d_in[6];
    const float* Nv     = (const float*)d_in[7];
    float* out          = (float*)d_out;

    const size_t need = (size_t)(CHUNKS - 1) * 4 * BCOLS * sizeof(float); // ~3.9 MB
    if (ws_size < need) {
        seir_mono<<<dim3(BCOLS / 64), dim3(64), 0, stream>>>(
            X, w_beta, w_gamma, w_sigma, S0, I0, R0, Nv, out);
        return;
    }

    float* wsp = (float*)d_ws;
    seir_pass1<<<dim3(BCOLS / 64), dim3(64), 0, stream>>>(
        X, w_beta, w_gamma, w_sigma, S0, I0, R0, Nv, wsp);
    seir_pass2<<<dim3(BCOLS / 64, CHUNKS), dim3(64), 0, stream>>>(
        X, w_beta, w_gamma, w_sigma, S0, I0, R0, Nv, wsp, out);
}